// Round 12
// baseline (146.160 us; speedup 1.0000x reference)
//
#include <hip/hip_runtime.h>

#define PEPS  1e-5f
#define LOG2E 1.4426950408889634f

__device__ __forceinline__ float fast_rcp(float x) { return __builtin_amdgcn_rcpf(x); }

// Pair-shared sigmoid blend: one v_rcp per two elements (trans-pipe relief).
__device__ __forceinline__ void patch_pair(float& x, float& y, float nrs2, float mrs) {
    const float tx = fminf(fmaf(x, nrs2, mrs), 60.0f);
    const float ty = fminf(fmaf(y, nrs2, mrs), 60.0f);
    const float ex = __builtin_amdgcn_exp2f(tx);
    const float ey = __builtin_amdgcn_exp2f(ty);
    const float ax = 1.0f + ex;
    const float ay = 1.0f + ey;
    const float r  = fast_rcp(ax * ay);
    x = x * fmaf(0.5f, r * ay, 0.5f);
    y = y * fmaf(0.5f, r * ax, 0.5f);
}

__device__ __forceinline__ void patch_quad(float4& t, float nrs2, float mrs) {
    patch_pair(t.x, t.y, nrs2, mrs);
    patch_pair(t.z, t.w, nrs2, mrs);
}

__device__ __forceinline__ void wave_reduce2(float& a, float& b) {
#pragma unroll
    for (int off = 32; off; off >>= 1) {
        a += __shfl_xor(a, off);
        b += __shfl_xor(b, off);
    }
}

// async global->LDS, 16 B per lane (LDS dest wave-uniform base, src per-lane).
__device__ __forceinline__ void gld_lds16(const float* g, float* l) {
    __builtin_amdgcn_global_load_lds(
        (const __attribute__((address_space(1))) void*)g,
        (__attribute__((address_space(3))) void*)l, 16, 0, 0);
}

// r11 base (113.5us) + two halves of ONE mechanism ("never stall on stores,
// never stall half the block"):
// (a) BALANCED B: tile holds the TOP 32 rows of each 64-row band; every wave
//     reads its patch's top half from LDS and bottom half from global (loads
//     issued first into v[8..15]). r8-r11's 8v8 split idled waves 0-7 ~4us
//     per image at the D barrier. (r9 bundled this with extra sched_barriers
//     and spilled; isolated here.)
// (b) RAW D BARRIER (lgkmcnt only): D's __syncthreads emitted vmcnt(0),
//     re-draining the previous image's 256KiB of H-stores (~2us/image) —
//     exactly the drain r11's counted-A tried to remove (null because of D).
//     D only needs LDS ordering; tile-overwrite safety comes from the barrier.
// Failure signatures: spill -> VGPR~64/SGPR=112/WRITE>280MB (revert a);
// absmax blowup -> race (revert b).
__global__ __launch_bounds__(1024) void fused_pyramid_pipe5(
    const float* __restrict__ in, float* __restrict__ out)
{
    constexpr int W   = 256;
    constexpr int IMG = W * W;                  // 65536 floats
    __shared__ float tile[32768];               // 128 KiB: band-top rows, interleaved
    __shared__ float redS[16], redQ[16];        // pass-2 partials
    __shared__ float redS2[16], redQ2[16];      // pass-3 partials

    const int tid   = threadIdx.x;
    const int wave  = tid >> 6;                 // 0..15 -> 4x4 grid of 64x64 patches
    const int lane  = tid & 63;
    const int pr    = wave >> 2;
    const int pc    = wave & 3;
    const int rlane = lane >> 4;                // 0..3
    const int c4    = lane & 15;
    const int bid   = blockIdx.x;

    // tile row t (0..127) <-> image row (t>>5)*64 + (t&31)  (top 32 of each band)
    // ---- prologue: prefetch image bid's band-tops --------------------------
    {
        const float* src = in + (size_t)bid * IMG;
#pragma unroll
        for (int i = 0; i < 8; ++i) {
            const int c  = wave * 8 + i;                // tile row
            const int gr = ((c >> 5) << 6) + (c & 31);  // image row
            gld_lds16(src + gr * W + lane * 4, &tile[c * W]);
        }
    }

    for (int k = 0; k < 4; ++k) {
        const int img = bid + k * 256;
        const float* in_img  = in  + (size_t)img * IMG;
        float*       out_img = out + (size_t)img * IMG;

        // A: wait own prefetch (counted: 8 oldest = prefetch; H-stores keep
        //    draining under B), then raw barrier.
        if (k == 0) { asm volatile("s_waitcnt vmcnt(0)" ::: "memory"); }
        else        { asm volatile("s_waitcnt vmcnt(16)" ::: "memory"); }
        __builtin_amdgcn_s_barrier();
        __builtin_amdgcn_sched_barrier(0);

        // B: bottom 32 rows of patch from global — issue loads first
        float4 v[16];
        const float* gl = in_img + (size_t)(pr * 64 + 32) * W + pc * 64;
#pragma unroll
        for (int u = 0; u < 8; ++u) {
            const int r = u * 4 + rlane;
            v[8 + u] = *reinterpret_cast<const float4*>(gl + (size_t)r * W + c4 * 4);
        }
        //    top 32 rows from LDS (tile rows pr*32..pr*32+31), sums meanwhile
        const float* tl = &tile[(pr * 32) * W + pc * 64];
        float s = 0.f, q = 0.f;
#pragma unroll
        for (int u = 0; u < 8; ++u) {
            const int r = u * 4 + rlane;
            const float4 t = *reinterpret_cast<const float4*>(tl + r * W + c4 * 4);
            v[u] = t;
            s += (t.x + t.y) + (t.z + t.w);
            q = fmaf(t.x, t.x, fmaf(t.y, t.y, fmaf(t.z, t.z, fmaf(t.w, t.w, q))));
        }
#pragma unroll
        for (int u = 8; u < 16; ++u) {
            const float4 t = v[u];
            s += (t.x + t.y) + (t.z + t.w);
            q = fmaf(t.x, t.x, fmaf(t.y, t.y, fmaf(t.z, t.z, fmaf(t.w, t.w, q))));
        }

        // C: pass 1 (s=64), wave-local
        wave_reduce2(s, q);
        float m  = s * (1.0f / 4096.0f);
        float rs = rsqrtf(fmaf(-m, m, q * (1.0f / 4096.0f)) + PEPS);
        float nrs2 = rs * -LOG2E;
        float mrs  = m * rs * LOG2E;

        float s2 = 0.f, q2 = 0.f;
#pragma unroll
        for (int u = 0; u < 16; ++u) {
            float4 t = v[u];
            patch_quad(t, nrs2, mrs);
            v[u] = t;
            s2 += (t.x + t.y) + (t.z + t.w);
            q2 = fmaf(t.x, t.x, fmaf(t.y, t.y, fmaf(t.z, t.z, fmaf(t.w, t.w, q2))));
        }

        // D: publish pass-2 partials; raw barrier, LDS-ordering only
        //    (no vmcnt drain — previous image's stores stay in flight)
        wave_reduce2(s2, q2);
        if (lane == 0) { redS[wave] = s2; redQ[wave] = q2; }
        asm volatile("s_waitcnt lgkmcnt(0)" ::: "memory");
        __builtin_amdgcn_s_barrier();

        // E: kick off next image's band-top prefetch (flies under F/G/H)
        if (k < 3) {
            const float* src = in + (size_t)(bid + (k + 1) * 256) * IMG;
#pragma unroll
            for (int i = 0; i < 8; ++i) {
                const int c  = wave * 8 + i;
                const int gr = ((c >> 5) << 6) + (c & 31);
                gld_lds16(src + gr * W + lane * 4, &tile[c * W]);
            }
        }

        // F: pass 2 (s=128): 2x2 wave group
        const int w00 = wave & ~5;
        {
            const float S = (redS[w00] + redS[w00 + 1]) + (redS[w00 + 4] + redS[w00 + 5]);
            const float Q = (redQ[w00] + redQ[w00 + 1]) + (redQ[w00 + 4] + redQ[w00 + 5]);
            m  = S * (1.0f / 16384.0f);
            rs = rsqrtf(fmaf(-m, m, Q * (1.0f / 16384.0f)) + PEPS);
        }
        nrs2 = rs * -LOG2E;
        mrs  = m * rs * LOG2E;

        float s3 = 0.f, q3 = 0.f;
#pragma unroll
        for (int u = 0; u < 16; ++u) {
            float4 t = v[u];
            patch_quad(t, nrs2, mrs);
            v[u] = t;
            s3 += (t.x + t.y) + (t.z + t.w);
            q3 = fmaf(t.x, t.x, fmaf(t.y, t.y, fmaf(t.z, t.z, fmaf(t.w, t.w, q3))));
        }

        // G: pass 3 (s=256): publish partials; raw barrier (no vmcnt drain)
        wave_reduce2(s3, q3);
        if (lane == 0) { redS2[wave] = s3; redQ2[wave] = q3; }
        asm volatile("s_waitcnt lgkmcnt(0)" ::: "memory");
        __builtin_amdgcn_s_barrier();
        __builtin_amdgcn_sched_barrier(0);
        {
            float S = 0.f, Q = 0.f;
#pragma unroll
            for (int w = 0; w < 16; ++w) { S += redS2[w]; Q += redQ2[w]; }
            m  = S * (1.0f / 65536.0f);
            rs = rsqrtf(fmaf(-m, m, Q * (1.0f / 65536.0f)) + PEPS);
        }
        nrs2 = rs * -LOG2E;
        mrs  = m * rs * LOG2E;

        // H: apply pass 3 + store (v[0..7] = patch rows 0..31, v[8..15] = 32..63)
        {
            float* go = out_img + (size_t)(pr * 64) * W + pc * 64;
#pragma unroll
            for (int u = 0; u < 16; ++u) {
                const int r = ((u >> 3) << 5) + ((u & 7) << 2) + rlane;
                float4 t = v[u];
                patch_quad(t, nrs2, mrs);
                *reinterpret_cast<float4*>(go + (size_t)r * W + c4 * 4) = t;
            }
        }
    }
}

extern "C" void kernel_launch(void* const* d_in, const int* in_sizes, int n_in,
                              void* d_out, int out_size, void* d_ws, size_t ws_size,
                              hipStream_t stream)
{
    const float* x = (const float*)d_in[0];
    float* out = (float*)d_out;
    // 1024 images, 256 persistent blocks x 4 images each; no workspace needed.
    fused_pyramid_pipe5<<<256, 1024, 0, stream>>>(x, out);
}

// Round 13
// 128.556 us; speedup vs baseline: 1.1369x; 1.1369x over previous
//
#include <hip/hip_runtime.h>

#define PEPS  1e-5f
#define LOG2E 1.4426950408889634f

__device__ __forceinline__ float fast_rcp(float x) { return __builtin_amdgcn_rcpf(x); }

// Pair-shared sigmoid blend: one v_rcp per two elements (trans-pipe relief).
__device__ __forceinline__ void patch_pair(float& x, float& y, float nrs2, float mrs) {
    const float tx = fminf(fmaf(x, nrs2, mrs), 60.0f);
    const float ty = fminf(fmaf(y, nrs2, mrs), 60.0f);
    const float ex = __builtin_amdgcn_exp2f(tx);
    const float ey = __builtin_amdgcn_exp2f(ty);
    const float ax = 1.0f + ex;
    const float ay = 1.0f + ey;
    const float r  = fast_rcp(ax * ay);
    x = x * fmaf(0.5f, r * ay, 0.5f);
    y = y * fmaf(0.5f, r * ax, 0.5f);
}

__device__ __forceinline__ void patch_quad(float4& t, float nrs2, float mrs) {
    patch_pair(t.x, t.y, nrs2, mrs);
    patch_pair(t.z, t.w, nrs2, mrs);
}

__device__ __forceinline__ void wave_reduce2(float& a, float& b) {
#pragma unroll
    for (int off = 32; off; off >>= 1) {
        a += __shfl_xor(a, off);
        b += __shfl_xor(b, off);
    }
}

// LDS-SLAB design (r13). Lessons enforced:
//  - r9/r12 (2 independent trials): any structure holding >=64 data floats in
//    registers at 1024 thr spills (VGPR=64/SGPR=112, +30us scratch). So keep
//    only HALF the patch in regs (v[8] = 32 VGPR); the other half lives in
//    PRIVATE LDS slots tile[u][tid] — each slot touched by exactly one thread,
//    so no barriers and no cross-thread hazards on data, ever.
//  - One block per image (grid=1024): all stores happen at block end, so the
//    two stat-publish __syncthreads (D,G) have nothing in flight to drain —
//    their implicit vmcnt(0) is free. Cross-image overlap = block turnover:
//    the ended block's fire-and-forget stores drain under the next block's
//    loads (separate waves = separate vmcnt counters).
//  - No prefetch, no gld_lds, no raw-barrier/vmcnt games, no workspace.
__global__ __launch_bounds__(1024) void fused_pyramid_slab(
    const float* __restrict__ in, float* __restrict__ out)
{
    constexpr int W   = 256;
    constexpr int IMG = W * W;
    __shared__ float4 tile[8 * 1024];          // 128 KiB, [u][tid] stride-1 slots
    __shared__ float redS[16], redQ[16];       // pass-2 partials
    __shared__ float redS2[16], redQ2[16];     // pass-3 partials

    const int tid   = threadIdx.x;
    const int wave  = tid >> 6;                // 0..15 -> 4x4 grid of 64x64 patches
    const int lane  = tid & 63;
    const int pr    = wave >> 2;
    const int pc    = wave & 3;
    const int rlane = lane >> 4;               // 0..3
    const int c4    = lane & 15;

    const size_t base = (size_t)blockIdx.x * IMG + (size_t)(pr * 64) * W + pc * 64;
    const float* gtop = in + base;             // patch rows 0..31
    const float* gbot = in + base + 32 * W;    // patch rows 32..63

    // ---- B: load. Bottom half -> v[8]; top half -> sums + private LDS slot.
    float4 v[8];
#pragma unroll
    for (int u = 0; u < 8; ++u) {
        const int r = u * 4 + rlane;
        v[u] = *reinterpret_cast<const float4*>(gbot + (size_t)r * W + c4 * 4);
    }
    float s = 0.f, q = 0.f;
#pragma unroll
    for (int u = 0; u < 8; ++u) {
        const int r = u * 4 + rlane;
        const float4 t = *reinterpret_cast<const float4*>(gtop + (size_t)r * W + c4 * 4);
        tile[u * 1024 + tid] = t;
        s += (t.x + t.y) + (t.z + t.w);
        q = fmaf(t.x, t.x, fmaf(t.y, t.y, fmaf(t.z, t.z, fmaf(t.w, t.w, q))));
    }
#pragma unroll
    for (int u = 0; u < 8; ++u) {
        const float4 t = v[u];
        s += (t.x + t.y) + (t.z + t.w);
        q = fmaf(t.x, t.x, fmaf(t.y, t.y, fmaf(t.z, t.z, fmaf(t.w, t.w, q))));
    }

    // ---- C: pass 1 (s=64), wave-local stats; apply to regs + LDS slots.
    wave_reduce2(s, q);
    float m  = s * (1.0f / 4096.0f);
    float rs = rsqrtf(fmaf(-m, m, q * (1.0f / 4096.0f)) + PEPS);
    float nrs2 = rs * -LOG2E;
    float mrs  = m * rs * LOG2E;

    float s2 = 0.f, q2 = 0.f;
#pragma unroll
    for (int u = 0; u < 8; ++u) {
        float4 t = v[u];
        patch_quad(t, nrs2, mrs);
        v[u] = t;
        s2 += (t.x + t.y) + (t.z + t.w);
        q2 = fmaf(t.x, t.x, fmaf(t.y, t.y, fmaf(t.z, t.z, fmaf(t.w, t.w, q2))));
    }
#pragma unroll
    for (int u = 0; u < 8; ++u) {
        float4 t = tile[u * 1024 + tid];
        patch_quad(t, nrs2, mrs);
        tile[u * 1024 + tid] = t;
        s2 += (t.x + t.y) + (t.z + t.w);
        q2 = fmaf(t.x, t.x, fmaf(t.y, t.y, fmaf(t.z, t.z, fmaf(t.w, t.w, q2))));
    }

    // ---- D: pass 2 (s=128) stats via LDS publish (vmcnt(0) here is free:
    //          no stores in flight yet).
    wave_reduce2(s2, q2);
    if (lane == 0) { redS[wave] = s2; redQ[wave] = q2; }
    __syncthreads();
    const int w00 = wave & ~5;
    {
        const float S = (redS[w00] + redS[w00 + 1]) + (redS[w00 + 4] + redS[w00 + 5]);
        const float Q = (redQ[w00] + redQ[w00 + 1]) + (redQ[w00 + 4] + redQ[w00 + 5]);
        m  = S * (1.0f / 16384.0f);
        rs = rsqrtf(fmaf(-m, m, Q * (1.0f / 16384.0f)) + PEPS);
    }
    nrs2 = rs * -LOG2E;
    mrs  = m * rs * LOG2E;

    // ---- F: apply pass 2 to regs + LDS slots, accumulate pass-3 sums.
    float s3 = 0.f, q3 = 0.f;
#pragma unroll
    for (int u = 0; u < 8; ++u) {
        float4 t = v[u];
        patch_quad(t, nrs2, mrs);
        v[u] = t;
        s3 += (t.x + t.y) + (t.z + t.w);
        q3 = fmaf(t.x, t.x, fmaf(t.y, t.y, fmaf(t.z, t.z, fmaf(t.w, t.w, q3))));
    }
#pragma unroll
    for (int u = 0; u < 8; ++u) {
        float4 t = tile[u * 1024 + tid];
        patch_quad(t, nrs2, mrs);
        tile[u * 1024 + tid] = t;
        s3 += (t.x + t.y) + (t.z + t.w);
        q3 = fmaf(t.x, t.x, fmaf(t.y, t.y, fmaf(t.z, t.z, fmaf(t.w, t.w, q3))));
    }

    // ---- G: pass 3 (s=256) stats.
    wave_reduce2(s3, q3);
    if (lane == 0) { redS2[wave] = s3; redQ2[wave] = q3; }
    __syncthreads();
    {
        float S = 0.f, Q = 0.f;
#pragma unroll
        for (int w = 0; w < 16; ++w) { S += redS2[w]; Q += redQ2[w]; }
        m  = S * (1.0f / 65536.0f);
        rs = rsqrtf(fmaf(-m, m, Q * (1.0f / 65536.0f)) + PEPS);
    }
    nrs2 = rs * -LOG2E;
    mrs  = m * rs * LOG2E;

    // ---- H: apply pass 3 + store (fire-and-forget; block ends, stores drain
    //          under the next block's loads).
    float* obase = out + base;
#pragma unroll
    for (int u = 0; u < 8; ++u) {
        const int r = u * 4 + rlane;
        float4 t = v[u];
        patch_quad(t, nrs2, mrs);
        *reinterpret_cast<float4*>(obase + (size_t)(r + 32) * W + c4 * 4) = t;
    }
#pragma unroll
    for (int u = 0; u < 8; ++u) {
        const int r = u * 4 + rlane;
        float4 t = tile[u * 1024 + tid];
        patch_quad(t, nrs2, mrs);
        *reinterpret_cast<float4*>(obase + (size_t)r * W + c4 * 4) = t;
    }
}

extern "C" void kernel_launch(void* const* d_in, const int* in_sizes, int n_in,
                              void* d_out, int out_size, void* d_ws, size_t ws_size,
                              hipStream_t stream)
{
    const float* x = (const float*)d_in[0];
    float* out = (float*)d_out;
    // One block per image (16*64 = 1024 images); no workspace needed.
    fused_pyramid_slab<<<1024, 1024, 0, stream>>>(x, out);
}

// Round 14
// 113.047 us; speedup vs baseline: 1.2929x; 1.1372x over previous
//
#include <hip/hip_runtime.h>

#define PEPS  1e-5f
#define LOG2E 1.4426950408889634f

__device__ __forceinline__ float fast_rcp(float x) { return __builtin_amdgcn_rcpf(x); }

// Pair-shared sigmoid blend: one v_rcp per two elements (trans-pipe relief).
__device__ __forceinline__ void patch_pair(float& x, float& y, float nrs2, float mrs) {
    const float tx = fminf(fmaf(x, nrs2, mrs), 60.0f);
    const float ty = fminf(fmaf(y, nrs2, mrs), 60.0f);
    const float ex = __builtin_amdgcn_exp2f(tx);
    const float ey = __builtin_amdgcn_exp2f(ty);
    const float ax = 1.0f + ex;
    const float ay = 1.0f + ey;
    const float r  = fast_rcp(ax * ay);
    x = x * fmaf(0.5f, r * ay, 0.5f);
    y = y * fmaf(0.5f, r * ax, 0.5f);
}

__device__ __forceinline__ void patch_quad(float4& t, float nrs2, float mrs) {
    patch_pair(t.x, t.y, nrs2, mrs);
    patch_pair(t.z, t.w, nrs2, mrs);
}

__device__ __forceinline__ void wave_reduce2(float& a, float& b) {
#pragma unroll
    for (int off = 32; off; off >>= 1) {
        a += __shfl_xor(a, off);
        b += __shfl_xor(b, off);
    }
}

// async global->LDS, 16 B per lane (LDS dest wave-uniform base, src per-lane).
__device__ __forceinline__ void gld_lds16(const float* g, float* l) {
    __builtin_amdgcn_global_load_lds(
        (const __attribute__((address_space(1))) void*)g,
        (__attribute__((address_space(3))) void*)l, 16, 0, 0);
}

// r11 base (113.5us: counted-A + raw-G + patch_pair) with ONE isolated change:
// RAW D BARRIER (lgkmcnt(0) + s_barrier, no vmcnt drain). r11's D=__syncthreads
// re-drained the previous image's 256 KiB of H-stores (~2-4us/image) — the
// drain counted-A was meant to bypass (r11 null explained). r12 had this fix
// but bundled the balanced-B restructure which spilled (2nd conviction of
// balanced-B; kept 8v8 split here).
// Per-wave vmcnt FIFO at A(k): [8 prefetch(k), E(k-1)] older than [16 stores,
// H(k-1)] -> vmcnt(16) retires exactly the prefetch. Stores never force-drain;
// they retire under B(k)'s loads.
// Failure signatures: spill -> VGPR=64/SGPR=112/WRITE>280MB (revert this edit);
// absmax blowup -> barrier race (revert); dur unchanged -> D-drain theory wrong.
__global__ __launch_bounds__(1024) void fused_pyramid_pipe6(
    const float* __restrict__ in, float* __restrict__ out)
{
    constexpr int W   = 256;
    constexpr int IMG = W * W;                  // 65536 floats
    __shared__ float tile[32768];               // 128 KiB: rows 0..127 of current image
    __shared__ float redS[16], redQ[16];        // pass-2 partials
    __shared__ float redS2[16], redQ2[16];      // pass-3 partials

    const int tid   = threadIdx.x;
    const int wave  = tid >> 6;                 // 0..15 -> 4x4 grid of 64x64 patches
    const int lane  = tid & 63;
    const int pr    = wave >> 2;
    const int pc    = wave & 3;
    const int rlane = lane >> 4;                // row contribution from lane
    const int c4    = lane & 15;
    const int bid   = blockIdx.x;

    // ---- prologue: prefetch image bid's top half into LDS ------------------
    {
        const float* src = in + (size_t)bid * IMG;
#pragma unroll
        for (int i = 0; i < 8; ++i) {
            const int chunk = wave * 8 + i;     // 128 chunks x 1024 B cover 128 KiB
            gld_lds16(src + chunk * 256 + lane * 4, &tile[chunk * 256]);
        }
    }

    for (int k = 0; k < 4; ++k) {
        const int img = bid + k * 256;
        const float* in_img  = in  + (size_t)img * IMG;
        float*       out_img = out + (size_t)img * IMG;

        // A: wait own prefetch (counted — H-stores keep draining under B),
        //    then raw barrier.
        if (k == 0) { asm volatile("s_waitcnt vmcnt(0)" ::: "memory"); }
        else        { asm volatile("s_waitcnt vmcnt(16)" ::: "memory"); }
        __builtin_amdgcn_s_barrier();
        __builtin_amdgcn_sched_barrier(0);

        // B: load v[16] + pass-1 sums. Top waves from LDS, bottom from global.
        float4 v[16];
        float s = 0.f, q = 0.f;
        if (wave < 8) {
            const float* tl = &tile[(pr * 64) * W + pc * 64];
#pragma unroll
            for (int u = 0; u < 16; ++u) {
                const int r = u * 4 + rlane;
                const float4 t = *reinterpret_cast<const float4*>(tl + r * W + c4 * 4);
                v[u] = t;
                s += (t.x + t.y) + (t.z + t.w);
                q = fmaf(t.x, t.x, fmaf(t.y, t.y, fmaf(t.z, t.z, fmaf(t.w, t.w, q))));
            }
        } else {
            const float* gl = in_img + (size_t)(pr * 64) * W + pc * 64;
#pragma unroll
            for (int u = 0; u < 16; ++u) {
                const int r = u * 4 + rlane;
                const float4 t = *reinterpret_cast<const float4*>(gl + (size_t)r * W + c4 * 4);
                v[u] = t;
                s += (t.x + t.y) + (t.z + t.w);
                q = fmaf(t.x, t.x, fmaf(t.y, t.y, fmaf(t.z, t.z, fmaf(t.w, t.w, q))));
            }
        }

        // C: pass 1 (s=64), wave-local
        wave_reduce2(s, q);
        float m  = s * (1.0f / 4096.0f);
        float rs = rsqrtf(fmaf(-m, m, q * (1.0f / 4096.0f)) + PEPS);
        float nrs2 = rs * -LOG2E;
        float mrs  = m * rs * LOG2E;

        float s2 = 0.f, q2 = 0.f;
#pragma unroll
        for (int u = 0; u < 16; ++u) {
            float4 t = v[u];
            patch_quad(t, nrs2, mrs);
            v[u] = t;
            s2 += (t.x + t.y) + (t.z + t.w);
            q2 = fmaf(t.x, t.x, fmaf(t.y, t.y, fmaf(t.z, t.z, fmaf(t.w, t.w, q2))));
        }

        // D: publish pass-2 partials; RAW barrier (LDS ordering only — the
        //    previous image's stores stay in flight; the one change vs r11)
        wave_reduce2(s2, q2);
        if (lane == 0) { redS[wave] = s2; redQ[wave] = q2; }
        asm volatile("s_waitcnt lgkmcnt(0)" ::: "memory");
        __builtin_amdgcn_s_barrier();

        // E: kick off next image's top-half prefetch (flies under F/G/H)
        if (k < 3) {
            const float* src = in + (size_t)(bid + (k + 1) * 256) * IMG;
#pragma unroll
            for (int i = 0; i < 8; ++i) {
                const int chunk = wave * 8 + i;
                gld_lds16(src + chunk * 256 + lane * 4, &tile[chunk * 256]);
            }
        }

        // F: pass 2 (s=128): 2x2 wave group
        const int w00 = wave & ~5;
        {
            const float S = (redS[w00] + redS[w00 + 1]) + (redS[w00 + 4] + redS[w00 + 5]);
            const float Q = (redQ[w00] + redQ[w00 + 1]) + (redQ[w00 + 4] + redQ[w00 + 5]);
            m  = S * (1.0f / 16384.0f);
            rs = rsqrtf(fmaf(-m, m, Q * (1.0f / 16384.0f)) + PEPS);
        }
        nrs2 = rs * -LOG2E;
        mrs  = m * rs * LOG2E;

        float s3 = 0.f, q3 = 0.f;
#pragma unroll
        for (int u = 0; u < 16; ++u) {
            float4 t = v[u];
            patch_quad(t, nrs2, mrs);
            v[u] = t;
            s3 += (t.x + t.y) + (t.z + t.w);
            q3 = fmaf(t.x, t.x, fmaf(t.y, t.y, fmaf(t.z, t.z, fmaf(t.w, t.w, q3))));
        }

        // G: pass 3 (s=256): publish partials; raw barrier (no vmcnt drain)
        wave_reduce2(s3, q3);
        if (lane == 0) { redS2[wave] = s3; redQ2[wave] = q3; }
        asm volatile("s_waitcnt lgkmcnt(0)" ::: "memory");
        __builtin_amdgcn_s_barrier();
        __builtin_amdgcn_sched_barrier(0);
        {
            float S = 0.f, Q = 0.f;
#pragma unroll
            for (int w = 0; w < 16; ++w) { S += redS2[w]; Q += redQ2[w]; }
            m  = S * (1.0f / 65536.0f);
            rs = rsqrtf(fmaf(-m, m, Q * (1.0f / 65536.0f)) + PEPS);
        }
        nrs2 = rs * -LOG2E;
        mrs  = m * rs * LOG2E;

        // H: apply pass 3 + store
        {
            float* go = out_img + (size_t)(pr * 64) * W + pc * 64;
#pragma unroll
            for (int u = 0; u < 16; ++u) {
                const int r = u * 4 + rlane;
                float4 t = v[u];
                patch_quad(t, nrs2, mrs);
                *reinterpret_cast<float4*>(go + (size_t)r * W + c4 * 4) = t;
            }
        }
    }
}

extern "C" void kernel_launch(void* const* d_in, const int* in_sizes, int n_in,
                              void* d_out, int out_size, void* d_ws, size_t ws_size,
                              hipStream_t stream)
{
    const float* x = (const float*)d_in[0];
    float* out = (float*)d_out;
    // 1024 images, 256 persistent blocks x 4 images each; no workspace needed.
    fused_pyramid_pipe6<<<256, 1024, 0, stream>>>(x, out);
}